// Round 9
// baseline (512.509 us; speedup 1.0000x reference)
//
#include <hip/hip_runtime.h>
#include <hip/hip_fp16.h>

#define N_NODES 50000
#define DIM 128
#define NE 800000
#define MAXD 48
#define CAP 64
#define NGRP (N_NODES/16)
#define NPAIR ((NGRP+1)/2)
#define NBLK ((N_NODES+255)/256)
#define GRUGRID (NPAIR/2)  // 781 -> use (NPAIR+1)/2=782

typedef _Float16 f16x8 __attribute__((ext_vector_type(8)));
typedef float f32x4 __attribute__((ext_vector_type(4)));

__device__ __forceinline__ float sigmf(float x){
  return __builtin_amdgcn_rcpf(1.f + __builtin_amdgcn_exp2f(-1.4426950408889634f * x));
}
__device__ __forceinline__ float tanh_fast(float x){
  float e = __builtin_amdgcn_exp2f(2.8853900817779268f * x);
  return 1.f - 2.f * __builtin_amdgcn_rcpf(e + 1.f);
}
__device__ __forceinline__ unsigned short f2h(float f){
  union{_Float16 h; unsigned short s;} c; c.h=(_Float16)f; return c.s;
}
__device__ __forceinline__ float h2f(unsigned short u){
  union{unsigned short s; _Float16 h;} c; c.s=u; return (float)c.h;
}

__global__ void kZero(int* p, int n){
  int i = blockIdx.x*blockDim.x + threadIdx.x;
  if(i<n) p[i]=0;
}

__global__ void kColStats(const float* __restrict__ feat, float* __restrict__ P, float* __restrict__ P2){
  int d = threadIdx.x; int b = blockIdx.x;
  float s=0.f, s2=0.f;
  for(int r=b; r<N_NODES; r+=256){ float v = feat[r*DIM+d]; s+=v; s2+=v*v; }
  P[b*DIM+d]=s; P2[b*DIM+d]=s2;
}

__global__ void kFinStats(const float* __restrict__ P, const float* __restrict__ P2,
                          const float* __restrict__ gamma, const float* __restrict__ beta,
                          float* __restrict__ scale, float* __restrict__ shift){
  int d = threadIdx.x;
  float s=0.f, s2=0.f;
  for(int b=0;b<256;b++){ s+=P[b*DIM+d]; s2+=P2[b*DIM+d]; }
  float mu = s/(float)N_NODES;
  float var = s2/(float)N_NODES - mu*mu;
  float rs = rsqrtf(var + 1e-5f);
  float sc = rs*gamma[d];
  scale[d]=sc; shift[d]=beta[d]-mu*sc;
}

__global__ void kEdges(const int* __restrict__ dst, int* __restrict__ cnt, int* __restrict__ elist){
  for(int e = blockIdx.x*blockDim.x+threadIdx.x; e < NE; e += gridDim.x*blockDim.x){
    int d = dst[e];
    int slot = atomicAdd(&cnt[d],1);
    if(slot < CAP) elist[(size_t)d*CAP+slot] = e;
  }
}

// One wave per node: 64-lane bitonic sort of edge ids, then resolve to src. No atomics.
__global__ __launch_bounds__(256) void kSortW(const int* __restrict__ src, const int* __restrict__ cnt,
    int* __restrict__ elist, int* __restrict__ len){
  int n = blockIdx.x*4 + (threadIdx.x>>6);
  if(n>=N_NODES) return;
  int l = threadIdx.x&63;
  int m = cnt[n]; m = m>CAP? CAP : m;
  int* el = elist + (size_t)n*CAP;
  int v = (l<m)? el[l] : 0x7fffffff;
  #pragma unroll
  for(int k=2;k<=64;k<<=1){
    #pragma unroll
    for(int j=k>>1;j>0;j>>=1){
      int u = __shfl_xor(v,j);
      bool up = ((l&k)==0);
      bool lower = ((l&j)==0);
      int mn = v<u? v:u, mx = v<u? u:v;
      v = (lower==up)? mn : mx;
    }
  }
  int L = m<MAXD? m : MAXD;
  if(l==0) len[n]=L;
  if(l<L) el[l] = src[v];
}

// Block-aggregated histogram: zero contended global atomics.
__global__ __launch_bounds__(256) void kHistB(const int* __restrict__ len, int* __restrict__ blockHist){
  __shared__ int lh[MAXD+1];
  const int b=blockIdx.x, tid=threadIdx.x;
  if(tid<=MAXD) lh[tid]=0;
  __syncthreads();
  const int n=b*256+tid;
  if(n<N_NODES) atomicAdd(&lh[len[n]],1);
  __syncthreads();
  if(tid<=MAXD) blockHist[tid*NBLK+b]=lh[tid];
}

// Single block: per-bin totals -> exclusive bin bases -> per-(bin,block) bases.
__global__ __launch_bounds__(64) void kScanB(const int* __restrict__ blockHist, int* __restrict__ blockBase){
  __shared__ int tot[MAXD+1];
  __shared__ int base[MAXD+1];
  const int tid=threadIdx.x;
  if(tid<=MAXD){
    int s=0;
    for(int b=0;b<NBLK;b++) s+=blockHist[tid*NBLK+b];
    tot[tid]=s;
  }
  __syncthreads();
  if(tid==0){ int s=0; for(int i=0;i<=MAXD;i++){ base[i]=s; s+=tot[i]; } }
  __syncthreads();
  if(tid<=MAXD){
    int run=base[tid];
    for(int b=0;b<NBLK;b++){ blockBase[tid*NBLK+b]=run; run+=blockHist[tid*NBLK+b]; }
  }
}

// Scatter using LDS-local ranks + precomputed bases (out[] is invariant to within-bin order).
__global__ __launch_bounds__(256) void kScatterB(const int* __restrict__ len,
    const int* __restrict__ blockBase, int* __restrict__ perm){
  __shared__ int lh[MAXD+1];
  const int b=blockIdx.x, tid=threadIdx.x;
  if(tid<=MAXD) lh[tid]=0;
  __syncthreads();
  const int n=b*256+tid;
  if(n<N_NODES){
    int bin=len[n];
    int lr=atomicAdd(&lh[bin],1);
    perm[blockBase[bin*NBLK+b]+lr]=n;
  }
}

// MFMA GEMM: GIh[n][j] = f16(x@Wih^T + bih + (j<256? bhh:0)), out[n] = x@Wself^T.
// BN folded into weights.
__global__ __launch_bounds__(256,1) void kXG2(const float* __restrict__ feat,
    const float* __restrict__ scale, const float* __restrict__ shift,
    const float* __restrict__ Wih, const float* __restrict__ bih, const float* __restrict__ bhh,
    const float* __restrict__ Wself,
    unsigned short* __restrict__ GIh, float* __restrict__ out)
{
  __shared__ unsigned short Wl[512*128];
  __shared__ float bL[512];
  const int tid=threadIdx.x, w=tid>>6, l=tid&63, g=l&15, q=l>>4;
  for(int i=tid;i<8192;i+=256){
    int j=i>>4, blk=i&15, d0=blk*8;
    const float* Wsrc=(j<384)? &Wih[(size_t)j*DIM] : &Wself[(size_t)(j-384)*DIM];
    float partial=0.f; unsigned u[4];
    #pragma unroll
    for(int e2=0;e2<4;e2++){
      float w0=Wsrc[d0+2*e2], w1=Wsrc[d0+2*e2+1];
      partial += shift[d0+2*e2]*w0 + shift[d0+2*e2+1]*w1;
      u[e2]=(unsigned)f2h(w0*scale[d0+2*e2]) | ((unsigned)f2h(w1*scale[d0+2*e2+1])<<16);
    }
    partial+=__shfl_xor(partial,1); partial+=__shfl_xor(partial,2);
    partial+=__shfl_xor(partial,4); partial+=__shfl_xor(partial,8);
    if((i&15)==0){
      float bb=partial;
      if(j<384) bb+=bih[j];
      if(j<256) bb+=bhh[j];
      bL[j]=bb;
    }
    char* dp=(char*)Wl + j*256 + ((blk^(j&7))<<4);
    *(uint4*)dp=make_uint4(u[0],u[1],u[2],u[3]);
  }
  __syncthreads();
  for(int grp=blockIdx.x*4+w; grp<NGRP; grp+=gridDim.x*4){
    const int n=grp*16+g;
    const float* fp=feat+(size_t)n*DIM;
    f16x8 Bf[4];
    #pragma unroll
    for(int ks=0;ks<4;ks++){
      float4 a=*(const float4*)&fp[32*ks+8*q];
      float4 b=*(const float4*)&fp[32*ks+8*q+4];
      f16x8 v; v[0]=(_Float16)a.x; v[1]=(_Float16)a.y; v[2]=(_Float16)a.z; v[3]=(_Float16)a.w;
      v[4]=(_Float16)b.x; v[5]=(_Float16)b.y; v[6]=(_Float16)b.z; v[7]=(_Float16)b.w;
      Bf[ks]=v;
    }
    for(int tile=0;tile<32;tile++){
      const int jbase=tile*16;
      f32x4 a={0.f,0.f,0.f,0.f};
      #pragma unroll
      for(int ks=0;ks<4;ks++){
        const char* ap=(const char*)Wl + (jbase+g)*256 + (((4*ks+q)^(g&7))<<4);
        a=__builtin_amdgcn_mfma_f32_16x16x32_f16(*(const f16x8*)ap,Bf[ks],a,0,0,0);
      }
      float4 bb=*(const float4*)&bL[jbase+4*q];
      if(tile<24){
        unsigned lo=(unsigned)f2h(a[0]+bb.x)|((unsigned)f2h(a[1]+bb.y)<<16);
        unsigned hi=(unsigned)f2h(a[2]+bb.z)|((unsigned)f2h(a[3]+bb.w)<<16);
        *(uint2*)&GIh[(size_t)n*384+jbase+4*q]=make_uint2(lo,hi);
      } else {
        float4 o; o.x=a[0]+bb.x; o.y=a[1]+bb.y; o.z=a[2]+bb.z; o.w=a[3]+bb.w;
        *(float4*)&out[(size_t)n*DIM + (jbase-384)+4*q]=o;
      }
    }
  }
}

// MFMA GRU, two-group pipeline per 4-wave block; FOLDED pair assignment for load balance:
// block b does pair b (short) then pair NPAIR-1-b (long); sums ~constant since degree-sorted.
__global__ __launch_bounds__(256,2) void kGruM(const unsigned short* __restrict__ GIh,
    const int* __restrict__ elist, const int* __restrict__ len, const int* __restrict__ perm,
    const float* __restrict__ Whh, const float* __restrict__ bhh,
    const float* __restrict__ Wneigh, float* __restrict__ out)
{
  __shared__ unsigned short hbuf[2][2][2][16][128]; // [grp][buf][plane][g][d] 32KB, swizzled rows
  const int tid=threadIdx.x, w=tid>>6, l=tid&63, g=l&15, q=l>>4;

  f16x8 Wf[6][4];
  #pragma unroll
  for(int fi=0;fi<6;fi++){
    const int gt=fi>>1, tt=fi&1;
    const int j=gt*128+32*w+16*tt+g;
    #pragma unroll
    for(int ks=0;ks<4;ks++){
      const float* p=&Whh[j*DIM+32*ks+8*q];
      f16x8 v;
      #pragma unroll
      for(int e=0;e<8;e++) v[e]=(_Float16)p[e];
      Wf[fi][ks]=v;
    }
  }
  float bhn[2][4];
  #pragma unroll
  for(int tt=0;tt<2;tt++)
    #pragma unroll
    for(int r=0;r<4;r++) bhn[tt][r]=bhh[256+32*w+16*tt+4*q+r];

  for(int rep=0; rep<2; rep++){
    const int gp = rep ? (NPAIR-1-(int)blockIdx.x) : (int)blockIdx.x;
    if(rep && gp<=(int)blockIdx.x) break;   // midpoint / duplicate guard
    if(gp>=NPAIR) continue;
    __syncthreads();
    for(int i=tid;i<2048;i+=256) ((uint4*)hbuf)[i]=make_uint4(0,0,0,0);
    const int nA=perm[(2*gp)*16+g];
    const bool gvB=(2*gp+1)<NGRP;
    const int nB=gvB? perm[(2*gp+1)*16+g]:0;
    const int LA=len[nA];
    const int LB=gvB? len[nB]:0;
    int T=LA>LB?LA:LB;
    T=max(T,__shfl_xor(T,1)); T=max(T,__shfl_xor(T,2));
    T=max(T,__shfl_xor(T,4)); T=max(T,__shfl_xor(T,8));
    __syncthreads();
    if(T==0) continue;
    const int* eA=elist+(size_t)nA*CAP;
    const int* eB=elist+(size_t)nB*CAP;
    int sNA, sNB;
    uint2 giA[6], giB[6];
    {
      int s0=(LA>0)?eA[0]:0;
      sNA=(LA>1)?eA[1]:s0;
      const unsigned short* gpp=GIh+(size_t)s0*384;
      #pragma unroll
      for(int fi=0;fi<6;fi++){ const int gt=fi>>1, tt=fi&1;
        giA[fi]=*(const uint2*)&gpp[gt*128+32*w+16*tt+4*q]; }
      int s0b=(LB>0)?eB[0]:0;
      sNB=(LB>1)?eB[1]:s0b;
      const unsigned short* gpb=GIh+(size_t)s0b*384;
      #pragma unroll
      for(int fi=0;fi<6;fi++){ const int gt=fi>>1, tt=fi&1;
        giB[fi]=*(const uint2*)&gpb[gt*128+32*w+16*tt+4*q]; }
    }
    float hA[2][4]={{0.f,0.f,0.f,0.f},{0.f,0.f,0.f,0.f}};
    float hB[2][4]={{0.f,0.f,0.f,0.f},{0.f,0.f,0.f,0.f}};
    for(int t=0;t<T;t++){
      const int cb=t&1, cbn=cb^1;
      // ================= group A =================
      {
        f16x8 Bf[4][2];
        #pragma unroll
        for(int ks=0;ks<4;ks++)
          #pragma unroll
          for(int p=0;p<2;p++){
            const char* bp=(const char*)hbuf + (((0*2+cb)*2+p)*16+g)*256 + (((4*ks+q)^(g&7))<<4);
            Bf[ks][p]=*(const f16x8*)bp;
          }
        f32x4 acc[6];
        #pragma unroll
        for(int fi=0;fi<6;fi++){
          f32x4 a={0.f,0.f,0.f,0.f};
          #pragma unroll
          for(int ks=0;ks<4;ks++) a=__builtin_amdgcn_mfma_f32_16x16x32_f16(Wf[fi][ks],Bf[ks][1],a,0,0,0);
          #pragma unroll
          for(int ks=0;ks<4;ks++) a=__builtin_amdgcn_mfma_f32_16x16x32_f16(Wf[fi][ks],Bf[ks][0],a,0,0,0);
          acc[fi]=a;
        }
        float gv[6][4];
        #pragma unroll
        for(int fi=0;fi<6;fi++){
          gv[fi][0]=h2f((unsigned short)(giA[fi].x&0xffffu));
          gv[fi][1]=h2f((unsigned short)(giA[fi].x>>16));
          gv[fi][2]=h2f((unsigned short)(giA[fi].y&0xffffu));
          gv[fi][3]=h2f((unsigned short)(giA[fi].y>>16));
        }
        if(t+1<T){
          const unsigned short* gpp=GIh+(size_t)sNA*384;
          #pragma unroll
          for(int fi=0;fi<6;fi++){ const int gt=fi>>1, tt=fi&1;
            giA[fi]=*(const uint2*)&gpp[gt*128+32*w+16*tt+4*q]; }
        }
        int ii=t+2; ii=(ii>LA-1)?(LA-1):ii; ii=(ii<0)?0:ii;
        const int sA2=(LA>0)?eA[ii]:0;
        const bool act=(t<LA);
        #pragma unroll
        for(int tt=0;tt<2;tt++)
          #pragma unroll
          for(int r=0;r<4;r++){
            float rr=sigmf(gv[tt][r]+acc[tt][r]);
            float zz=sigmf(gv[2+tt][r]+acc[2+tt][r]);
            float nn=tanh_fast(gv[4+tt][r]+rr*(acc[4+tt][r]+bhn[tt][r]));
            float hn=(1.f-zz)*nn+zz*hA[tt][r];
            hA[tt][r]=act?hn:hA[tt][r];
          }
        #pragma unroll
        for(int tt=0;tt<2;tt++){
          unsigned short a0=f2h(hA[tt][0]),a1=f2h(hA[tt][1]),a2=f2h(hA[tt][2]),a3=f2h(hA[tt][3]);
          unsigned short b0=f2h(hA[tt][0]-h2f(a0)),b1=f2h(hA[tt][1]-h2f(a1));
          unsigned short b2=f2h(hA[tt][2]-h2f(a2)),b3=f2h(hA[tt][3]-h2f(a3));
          const int blk=((4*w+2*tt+(q>>1))^(g&7));
          const int sub=8*(q&1);
          char* p0=(char*)hbuf + (((0*2+cbn)*2+0)*16+g)*256 + blk*16 + sub;
          char* p1=(char*)hbuf + (((0*2+cbn)*2+1)*16+g)*256 + blk*16 + sub;
          *(uint2*)p0=make_uint2((unsigned)a0|((unsigned)a1<<16),(unsigned)a2|((unsigned)a3<<16));
          *(uint2*)p1=make_uint2((unsigned)b0|((unsigned)b1<<16),(unsigned)b2|((unsigned)b3<<16));
        }
        sNA=sA2;
      }
      // ================= group B =================
      {
        f16x8 Bf[4][2];
        #pragma unroll
        for(int ks=0;ks<4;ks++)
          #pragma unroll
          for(int p=0;p<2;p++){
            const char* bp=(const char*)hbuf + (((1*2+cb)*2+p)*16+g)*256 + (((4*ks+q)^(g&7))<<4);
            Bf[ks][p]=*(const f16x8*)bp;
          }
        f32x4 acc[6];
        #pragma unroll
        for(int fi=0;fi<6;fi++){
          f32x4 a={0.f,0.f,0.f,0.f};
          #pragma unroll
          for(int ks=0;ks<4;ks++) a=__builtin_amdgcn_mfma_f32_16x16x32_f16(Wf[fi][ks],Bf[ks][1],a,0,0,0);
          #pragma unroll
          for(int ks=0;ks<4;ks++) a=__builtin_amdgcn_mfma_f32_16x16x32_f16(Wf[fi][ks],Bf[ks][0],a,0,0,0);
          acc[fi]=a;
        }
        float gv[6][4];
        #pragma unroll
        for(int fi=0;fi<6;fi++){
          gv[fi][0]=h2f((unsigned short)(giB[fi].x&0xffffu));
          gv[fi][1]=h2f((unsigned short)(giB[fi].x>>16));
          gv[fi][2]=h2f((unsigned short)(giB[fi].y&0xffffu));
          gv[fi][3]=h2f((unsigned short)(giB[fi].y>>16));
        }
        if(t+1<T){
          const unsigned short* gpp=GIh+(size_t)sNB*384;
          #pragma unroll
          for(int fi=0;fi<6;fi++){ const int gt=fi>>1, tt=fi&1;
            giB[fi]=*(const uint2*)&gpp[gt*128+32*w+16*tt+4*q]; }
        }
        int ii=t+2; ii=(ii>LB-1)?(LB-1):ii; ii=(ii<0)?0:ii;
        const int sB2=(LB>0)?eB[ii]:0;
        const bool act=(t<LB);
        #pragma unroll
        for(int tt=0;tt<2;tt++)
          #pragma unroll
          for(int r=0;r<4;r++){
            float rr=sigmf(gv[tt][r]+acc[tt][r]);
            float zz=sigmf(gv[2+tt][r]+acc[2+tt][r]);
            float nn=tanh_fast(gv[4+tt][r]+rr*(acc[4+tt][r]+bhn[tt][r]));
            float hn=(1.f-zz)*nn+zz*hB[tt][r];
            hB[tt][r]=act?hn:hB[tt][r];
          }
        #pragma unroll
        for(int tt=0;tt<2;tt++){
          unsigned short a0=f2h(hB[tt][0]),a1=f2h(hB[tt][1]),a2=f2h(hB[tt][2]),a3=f2h(hB[tt][3]);
          unsigned short b0=f2h(hB[tt][0]-h2f(a0)),b1=f2h(hB[tt][1]-h2f(a1));
          unsigned short b2=f2h(hB[tt][2]-h2f(a2)),b3=f2h(hB[tt][3]-h2f(a3));
          const int blk=((4*w+2*tt+(q>>1))^(g&7));
          const int sub=8*(q&1);
          char* p0=(char*)hbuf + (((1*2+cbn)*2+0)*16+g)*256 + blk*16 + sub;
          char* p1=(char*)hbuf + (((1*2+cbn)*2+1)*16+g)*256 + blk*16 + sub;
          *(uint2*)p0=make_uint2((unsigned)a0|((unsigned)a1<<16),(unsigned)a2|((unsigned)a3<<16));
          *(uint2*)p1=make_uint2((unsigned)b0|((unsigned)b1<<16),(unsigned)b2|((unsigned)b3<<16));
        }
        sNB=sB2;
      }
      __syncthreads();
    }
    const int fb=T&1;
    // epilogue: out += W_neigh · h_final (hi+lo planes); A-frags from global (L2-hot)
    #pragma unroll
    for(int tt=0;tt<2;tt++){
      f32x4 a={0.f,0.f,0.f,0.f};
      #pragma unroll
      for(int ks=0;ks<4;ks++){
        const float* wp=&Wneigh[(size_t)(32*w+16*tt+g)*DIM + 32*ks+8*q];
        float4 w0=*(const float4*)wp, w1=*(const float4*)(wp+4);
        f16x8 Af; Af[0]=(_Float16)w0.x; Af[1]=(_Float16)w0.y; Af[2]=(_Float16)w0.z; Af[3]=(_Float16)w0.w;
        Af[4]=(_Float16)w1.x; Af[5]=(_Float16)w1.y; Af[6]=(_Float16)w1.z; Af[7]=(_Float16)w1.w;
        const char* bl=(const char*)hbuf + (((0*2+fb)*2+1)*16+g)*256 + (((4*ks+q)^(g&7))<<4);
        const char* bhp=(const char*)hbuf + (((0*2+fb)*2+0)*16+g)*256 + (((4*ks+q)^(g&7))<<4);
        a=__builtin_amdgcn_mfma_f32_16x16x32_f16(Af,*(const f16x8*)bl,a,0,0,0);
        a=__builtin_amdgcn_mfma_f32_16x16x32_f16(Af,*(const f16x8*)bhp,a,0,0,0);
      }
      float* po=&out[(size_t)nA*DIM + 32*w+16*tt+4*q];
      float4 cur=*(float4*)po;
      cur.x+=a[0]; cur.y+=a[1]; cur.z+=a[2]; cur.w+=a[3];
      *(float4*)po=cur;
    }
    if(gvB){
      #pragma unroll
      for(int tt=0;tt<2;tt++){
        f32x4 a={0.f,0.f,0.f,0.f};
        #pragma unroll
        for(int ks=0;ks<4;ks++){
          const float* wp=&Wneigh[(size_t)(32*w+16*tt+g)*DIM + 32*ks+8*q];
          float4 w0=*(const float4*)wp, w1=*(const float4*)(wp+4);
          f16x8 Af; Af[0]=(_Float16)w0.x; Af[1]=(_Float16)w0.y; Af[2]=(_Float16)w0.z; Af[3]=(_Float16)w0.w;
          Af[4]=(_Float16)w1.x; Af[5]=(_Float16)w1.y; Af[6]=(_Float16)w1.z; Af[7]=(_Float16)w1.w;
          const char* bl=(const char*)hbuf + (((1*2+fb)*2+1)*16+g)*256 + (((4*ks+q)^(g&7))<<4);
          const char* bhp=(const char*)hbuf + (((1*2+fb)*2+0)*16+g)*256 + (((4*ks+q)^(g&7))<<4);
          a=__builtin_amdgcn_mfma_f32_16x16x32_f16(Af,*(const f16x8*)bl,a,0,0,0);
          a=__builtin_amdgcn_mfma_f32_16x16x32_f16(Af,*(const f16x8*)bhp,a,0,0,0);
        }
        float* po=&out[(size_t)nB*DIM + 32*w+16*tt+4*q];
        float4 cur=*(float4*)po;
        cur.x+=a[0]; cur.y+=a[1]; cur.z+=a[2]; cur.w+=a[3];
        *(float4*)po=cur;
      }
    }
  }
}

extern "C" void kernel_launch(void* const* d_in, const int* in_sizes, int n_in,
                              void* d_out, int out_size, void* d_ws, size_t ws_size,
                              hipStream_t stream){
  const float* feat  = (const float*)d_in[0];
  const int*   src   = (const int*)d_in[1];
  const int*   dst   = (const int*)d_in[2];
  const float* gamma = (const float*)d_in[3];
  const float* beta  = (const float*)d_in[4];
  const float* Wih   = (const float*)d_in[5];
  const float* Whh   = (const float*)d_in[6];
  const float* bih   = (const float*)d_in[7];
  const float* bhh   = (const float*)d_in[8];
  const float* Wself = (const float*)d_in[9];
  const float* Wneigh= (const float*)d_in[10];
  float* out = (float*)d_out;

  char* ws = (char*)d_ws;
  size_t off = 0;
  auto alloc = [&](size_t bytes)->void*{ void* p = ws+off; off += (bytes+511)&~(size_t)511; return p; };
  float* P     = (float*)alloc(256*128*4);
  float* P2    = (float*)alloc(256*128*4);
  float* scale = (float*)alloc(512);
  float* shift = (float*)alloc(512);
  int*   cnt   = (int*)alloc((size_t)N_NODES*4);
  int*   lenp  = (int*)alloc((size_t)N_NODES*4);
  int*   blockHist = (int*)alloc((size_t)(MAXD+1)*NBLK*4);
  int*   blockBase = (int*)alloc((size_t)(MAXD+1)*NBLK*4);
  int*   perm  = (int*)alloc((size_t)N_NODES*4);
  int*   elist = (int*)alloc((size_t)N_NODES*CAP*4);
  unsigned short* GIh = (unsigned short*)alloc((size_t)N_NODES*384*2);

  kZero<<<(N_NODES+255)/256, 256, 0, stream>>>(cnt, N_NODES);
  kColStats<<<256,128,0,stream>>>(feat, P, P2);
  kFinStats<<<1,128,0,stream>>>(P,P2,gamma,beta,scale,shift);
  kEdges<<<1024,256,0,stream>>>(dst, cnt, elist);
  kSortW<<<(N_NODES+3)/4,256,0,stream>>>(src, cnt, elist, lenp);
  kHistB<<<NBLK,256,0,stream>>>(lenp, blockHist);
  kScanB<<<1,64,0,stream>>>(blockHist, blockBase);
  kScatterB<<<NBLK,256,0,stream>>>(lenp, blockBase, perm);
  kXG2<<<256,256,0,stream>>>(feat, scale, shift, Wih, bih, bhh, Wself, GIh, out);
  kGruM<<<(NPAIR+1)/2,256,0,stream>>>(GIh, elist, lenp, perm, Whh, bhh, Wneigh, out);
}

// Round 10
// 463.670 us; speedup vs baseline: 1.1053x; 1.1053x over previous
//
#include <hip/hip_runtime.h>
#include <hip/hip_fp16.h>

#define N_NODES 50000
#define DIM 128
#define NE 800000
#define MAXD 48
#define CAP 64
#define NGRP (N_NODES/16)
#define NPAIR ((NGRP+1)/2)
#define NBLK ((N_NODES+255)/256)

typedef _Float16 f16x8 __attribute__((ext_vector_type(8)));
typedef float f32x4 __attribute__((ext_vector_type(4)));

__device__ __forceinline__ float sigmf(float x){
  return __builtin_amdgcn_rcpf(1.f + __builtin_amdgcn_exp2f(-1.4426950408889634f * x));
}
__device__ __forceinline__ float tanh_fast(float x){
  float e = __builtin_amdgcn_exp2f(2.8853900817779268f * x);
  return 1.f - 2.f * __builtin_amdgcn_rcpf(e + 1.f);
}
__device__ __forceinline__ unsigned short f2h(float f){
  union{_Float16 h; unsigned short s;} c; c.h=(_Float16)f; return c.s;
}
__device__ __forceinline__ float h2f(unsigned short u){
  union{unsigned short s; _Float16 h;} c; c.s=u; return (float)c.h;
}

__global__ void kZero(int* p, int n){
  int i = blockIdx.x*blockDim.x + threadIdx.x;
  if(i<n) p[i]=0;
}

__global__ void kColStats(const float* __restrict__ feat, float* __restrict__ P, float* __restrict__ P2){
  int d = threadIdx.x; int b = blockIdx.x;
  float s=0.f, s2=0.f;
  for(int r=b; r<N_NODES; r+=256){ float v = feat[r*DIM+d]; s+=v; s2+=v*v; }
  P[b*DIM+d]=s; P2[b*DIM+d]=s2;
}

__global__ void kFinStats(const float* __restrict__ P, const float* __restrict__ P2,
                          const float* __restrict__ gamma, const float* __restrict__ beta,
                          float* __restrict__ scale, float* __restrict__ shift){
  int d = threadIdx.x;
  float s=0.f, s2=0.f;
  for(int b=0;b<256;b++){ s+=P[b*DIM+d]; s2+=P2[b*DIM+d]; }
  float mu = s/(float)N_NODES;
  float var = s2/(float)N_NODES - mu*mu;
  float rs = rsqrtf(var + 1e-5f);
  float sc = rs*gamma[d];
  scale[d]=sc; shift[d]=beta[d]-mu*sc;
}

__global__ void kEdges(const int* __restrict__ dst, int* __restrict__ cnt, int* __restrict__ elist){
  for(int e = blockIdx.x*blockDim.x+threadIdx.x; e < NE; e += gridDim.x*blockDim.x){
    int d = dst[e];
    int slot = atomicAdd(&cnt[d],1);
    if(slot < CAP) elist[(size_t)d*CAP+slot] = e;
  }
}

// One wave per node: 64-lane bitonic sort of edge ids, then resolve to src. No atomics.
__global__ __launch_bounds__(256) void kSortW(const int* __restrict__ src, const int* __restrict__ cnt,
    int* __restrict__ elist, int* __restrict__ len){
  int n = blockIdx.x*4 + (threadIdx.x>>6);
  if(n>=N_NODES) return;
  int l = threadIdx.x&63;
  int m = cnt[n]; m = m>CAP? CAP : m;
  int* el = elist + (size_t)n*CAP;
  int v = (l<m)? el[l] : 0x7fffffff;
  #pragma unroll
  for(int k=2;k<=64;k<<=1){
    #pragma unroll
    for(int j=k>>1;j>0;j>>=1){
      int u = __shfl_xor(v,j);
      bool up = ((l&k)==0);
      bool lower = ((l&j)==0);
      int mn = v<u? v:u, mx = v<u? u:v;
      v = (lower==up)? mn : mx;
    }
  }
  int L = m<MAXD? m : MAXD;
  if(l==0) len[n]=L;
  if(l<L) el[l] = src[v];
}

// Block-aggregated histogram: zero contended global atomics.
__global__ __launch_bounds__(256) void kHistB(const int* __restrict__ len, int* __restrict__ blockHist){
  __shared__ int lh[MAXD+1];
  const int b=blockIdx.x, tid=threadIdx.x;
  if(tid<=MAXD) lh[tid]=0;
  __syncthreads();
  const int n=b*256+tid;
  if(n<N_NODES) atomicAdd(&lh[len[n]],1);
  __syncthreads();
  if(tid<=MAXD) blockHist[tid*NBLK+b]=lh[tid];
}

// Single block: per-bin totals -> exclusive bin bases -> per-(bin,block) bases.
__global__ __launch_bounds__(64) void kScanB(const int* __restrict__ blockHist, int* __restrict__ blockBase){
  __shared__ int tot[MAXD+1];
  __shared__ int base[MAXD+1];
  const int tid=threadIdx.x;
  if(tid<=MAXD){
    int s=0;
    for(int b=0;b<NBLK;b++) s+=blockHist[tid*NBLK+b];
    tot[tid]=s;
  }
  __syncthreads();
  if(tid==0){ int s=0; for(int i=0;i<=MAXD;i++){ base[i]=s; s+=tot[i]; } }
  __syncthreads();
  if(tid<=MAXD){
    int run=base[tid];
    for(int b=0;b<NBLK;b++){ blockBase[tid*NBLK+b]=run; run+=blockHist[tid*NBLK+b]; }
  }
}

// Scatter using LDS-local ranks + precomputed bases (out[] is invariant to within-bin order).
__global__ __launch_bounds__(256) void kScatterB(const int* __restrict__ len,
    const int* __restrict__ blockBase, int* __restrict__ perm){
  __shared__ int lh[MAXD+1];
  const int b=blockIdx.x, tid=threadIdx.x;
  if(tid<=MAXD) lh[tid]=0;
  __syncthreads();
  const int n=b*256+tid;
  if(n<N_NODES){
    int bin=len[n];
    int lr=atomicAdd(&lh[bin],1);
    perm[blockBase[bin*NBLK+b]+lr]=n;
  }
}

// MFMA GEMM: GIh[n][j] = f16(x@Wih^T + bih + (j<256? bhh:0)), out[n] = x@Wself^T.
// BN folded into weights.
__global__ __launch_bounds__(256,1) void kXG2(const float* __restrict__ feat,
    const float* __restrict__ scale, const float* __restrict__ shift,
    const float* __restrict__ Wih, const float* __restrict__ bih, const float* __restrict__ bhh,
    const float* __restrict__ Wself,
    unsigned short* __restrict__ GIh, float* __restrict__ out)
{
  __shared__ unsigned short Wl[512*128];
  __shared__ float bL[512];
  const int tid=threadIdx.x, w=tid>>6, l=tid&63, g=l&15, q=l>>4;
  for(int i=tid;i<8192;i+=256){
    int j=i>>4, blk=i&15, d0=blk*8;
    const float* Wsrc=(j<384)? &Wih[(size_t)j*DIM] : &Wself[(size_t)(j-384)*DIM];
    float partial=0.f; unsigned u[4];
    #pragma unroll
    for(int e2=0;e2<4;e2++){
      float w0=Wsrc[d0+2*e2], w1=Wsrc[d0+2*e2+1];
      partial += shift[d0+2*e2]*w0 + shift[d0+2*e2+1]*w1;
      u[e2]=(unsigned)f2h(w0*scale[d0+2*e2]) | ((unsigned)f2h(w1*scale[d0+2*e2+1])<<16);
    }
    partial+=__shfl_xor(partial,1); partial+=__shfl_xor(partial,2);
    partial+=__shfl_xor(partial,4); partial+=__shfl_xor(partial,8);
    if((i&15)==0){
      float bb=partial;
      if(j<384) bb+=bih[j];
      if(j<256) bb+=bhh[j];
      bL[j]=bb;
    }
    char* dp=(char*)Wl + j*256 + ((blk^(j&7))<<4);
    *(uint4*)dp=make_uint4(u[0],u[1],u[2],u[3]);
  }
  __syncthreads();
  for(int grp=blockIdx.x*4+w; grp<NGRP; grp+=gridDim.x*4){
    const int n=grp*16+g;
    const float* fp=feat+(size_t)n*DIM;
    f16x8 Bf[4];
    #pragma unroll
    for(int ks=0;ks<4;ks++){
      float4 a=*(const float4*)&fp[32*ks+8*q];
      float4 b=*(const float4*)&fp[32*ks+8*q+4];
      f16x8 v; v[0]=(_Float16)a.x; v[1]=(_Float16)a.y; v[2]=(_Float16)a.z; v[3]=(_Float16)a.w;
      v[4]=(_Float16)b.x; v[5]=(_Float16)b.y; v[6]=(_Float16)b.z; v[7]=(_Float16)b.w;
      Bf[ks]=v;
    }
    for(int tile=0;tile<32;tile++){
      const int jbase=tile*16;
      f32x4 a={0.f,0.f,0.f,0.f};
      #pragma unroll
      for(int ks=0;ks<4;ks++){
        const char* ap=(const char*)Wl + (jbase+g)*256 + (((4*ks+q)^(g&7))<<4);
        a=__builtin_amdgcn_mfma_f32_16x16x32_f16(*(const f16x8*)ap,Bf[ks],a,0,0,0);
      }
      float4 bb=*(const float4*)&bL[jbase+4*q];
      if(tile<24){
        unsigned lo=(unsigned)f2h(a[0]+bb.x)|((unsigned)f2h(a[1]+bb.y)<<16);
        unsigned hi=(unsigned)f2h(a[2]+bb.z)|((unsigned)f2h(a[3]+bb.w)<<16);
        *(uint2*)&GIh[(size_t)n*384+jbase+4*q]=make_uint2(lo,hi);
      } else {
        float4 o; o.x=a[0]+bb.x; o.y=a[1]+bb.y; o.z=a[2]+bb.z; o.w=a[3]+bb.w;
        *(float4*)&out[(size_t)n*DIM + (jbase-384)+4*q]=o;
      }
    }
  }
}

// MFMA GRU, two-group pipeline per 4-wave block (R6 config: grid 512, WnL in LDS).
// LDS byte addresses hoisted out of the t-loop; grp/buf/plane strides are ds offset imms.
// hbuf layout [grp][buf][plane][g][d]: strides grp=16384, buf=8192, plane=4096, g=256.
__global__ __launch_bounds__(256,2) void kGruM(const unsigned short* __restrict__ GIh,
    const int* __restrict__ elist, const int* __restrict__ len, const int* __restrict__ perm,
    const float* __restrict__ Whh, const float* __restrict__ bhh,
    const float* __restrict__ Wneigh, float* __restrict__ out)
{
  __shared__ unsigned short hbuf[2][2][2][16][128]; // 32KB, swizzled rows
  __shared__ unsigned short WnL[128*128];           // 32KB swizzled
  const int tid=threadIdx.x, w=tid>>6, l=tid&63, g=l&15, q=l>>4;

  for(int i=tid;i<2048;i+=256){
    int j=i>>4, blk=i&15;
    const float* p=&Wneigh[(size_t)j*DIM + blk*8];
    unsigned u0=(unsigned)f2h(p[0])|((unsigned)f2h(p[1])<<16);
    unsigned u1=(unsigned)f2h(p[2])|((unsigned)f2h(p[3])<<16);
    unsigned u2=(unsigned)f2h(p[4])|((unsigned)f2h(p[5])<<16);
    unsigned u3=(unsigned)f2h(p[6])|((unsigned)f2h(p[7])<<16);
    char* dp=(char*)WnL + j*256 + ((blk^(j&7))<<4);
    *(uint4*)dp=make_uint4(u0,u1,u2,u3);
  }
  f16x8 Wf[6][4];
  #pragma unroll
  for(int fi=0;fi<6;fi++){
    const int gt=fi>>1, tt=fi&1;
    const int j=gt*128+32*w+16*tt+g;
    #pragma unroll
    for(int ks=0;ks<4;ks++){
      const float* p=&Whh[j*DIM+32*ks+8*q];
      f16x8 v;
      #pragma unroll
      for(int e=0;e<8;e++) v[e]=(_Float16)p[e];
      Wf[fi][ks]=v;
    }
  }
  float bhn[2][4];
  #pragma unroll
  for(int tt=0;tt<2;tt++)
    #pragma unroll
    for(int r=0;r<4;r++) bhn[tt][r]=bhh[256+32*w+16*tt+4*q+r];

  // Hoisted lane-constant LDS byte offsets (within hbuf):
  char* const hb=(char*)hbuf;
  int ra0 = g*256 + ((( 0+q)^(g&7))<<4);
  int ra1 = g*256 + ((( 4+q)^(g&7))<<4);
  int ra2 = g*256 + ((( 8+q)^(g&7))<<4);
  int ra3 = g*256 + (((12+q)^(g&7))<<4);
  const int wsub = 8*(q&1) + g*256;
  int wa0 = (((4*w+0+(q>>1))^(g&7))<<4) + wsub;  // tt=0
  int wa1 = (((4*w+2+(q>>1))^(g&7))<<4) + wsub;  // tt=1

  for(int gp=blockIdx.x; gp<NPAIR; gp+=gridDim.x){
    __syncthreads();
    for(int i=tid;i<2048;i+=256) ((uint4*)hbuf)[i]=make_uint4(0,0,0,0);
    const int nA=perm[(2*gp)*16+g];
    const bool gvB=(2*gp+1)<NGRP;
    const int nB=gvB? perm[(2*gp+1)*16+g]:0;
    const int LA=len[nA];
    const int LB=gvB? len[nB]:0;
    int T=LA>LB?LA:LB;
    T=max(T,__shfl_xor(T,1)); T=max(T,__shfl_xor(T,2));
    T=max(T,__shfl_xor(T,4)); T=max(T,__shfl_xor(T,8));
    __syncthreads();
    if(T==0) continue;
    const int* eA=elist+(size_t)nA*CAP;
    const int* eB=elist+(size_t)nB*CAP;
    int sNA, sNB;
    uint2 giA[6], giB[6];
    {
      int s0=(LA>0)?eA[0]:0;
      sNA=(LA>1)?eA[1]:s0;
      const unsigned short* gpp=GIh+(size_t)s0*384;
      #pragma unroll
      for(int fi=0;fi<6;fi++){ const int gt=fi>>1, tt=fi&1;
        giA[fi]=*(const uint2*)&gpp[gt*128+32*w+16*tt+4*q]; }
      int s0b=(LB>0)?eB[0]:0;
      sNB=(LB>1)?eB[1]:s0b;
      const unsigned short* gpb=GIh+(size_t)s0b*384;
      #pragma unroll
      for(int fi=0;fi<6;fi++){ const int gt=fi>>1, tt=fi&1;
        giB[fi]=*(const uint2*)&gpb[gt*128+32*w+16*tt+4*q]; }
    }
    float hA[2][4]={{0.f,0.f,0.f,0.f},{0.f,0.f,0.f,0.f}};
    float hB[2][4]={{0.f,0.f,0.f,0.f},{0.f,0.f,0.f,0.f}};
    for(int t=0;t<T;t++){
      const int off=(t&1)<<13, offn=off^8192;
      const char* rA0=hb+ra0+off; const char* rA1=hb+ra1+off;
      const char* rA2=hb+ra2+off; const char* rA3=hb+ra3+off;
      char* wA0=hb+wa0+offn; char* wA1=hb+wa1+offn;
      // ================= group A =================  (grp base 0)
      {
        f16x8 Bf[4][2];
        #pragma unroll
        for(int p=0;p<2;p++){
          Bf[0][p]=*(const f16x8*)(rA0 + p*4096);
          Bf[1][p]=*(const f16x8*)(rA1 + p*4096);
          Bf[2][p]=*(const f16x8*)(rA2 + p*4096);
          Bf[3][p]=*(const f16x8*)(rA3 + p*4096);
        }
        f32x4 acc[6];
        #pragma unroll
        for(int fi=0;fi<6;fi++){
          f32x4 a={0.f,0.f,0.f,0.f};
          #pragma unroll
          for(int ks=0;ks<4;ks++) a=__builtin_amdgcn_mfma_f32_16x16x32_f16(Wf[fi][ks],Bf[ks][1],a,0,0,0);
          #pragma unroll
          for(int ks=0;ks<4;ks++) a=__builtin_amdgcn_mfma_f32_16x16x32_f16(Wf[fi][ks],Bf[ks][0],a,0,0,0);
          acc[fi]=a;
        }
        float gv[6][4];
        #pragma unroll
        for(int fi=0;fi<6;fi++){
          gv[fi][0]=h2f((unsigned short)(giA[fi].x&0xffffu));
          gv[fi][1]=h2f((unsigned short)(giA[fi].x>>16));
          gv[fi][2]=h2f((unsigned short)(giA[fi].y&0xffffu));
          gv[fi][3]=h2f((unsigned short)(giA[fi].y>>16));
        }
        if(t+1<T){
          const unsigned short* gpp=GIh+(size_t)sNA*384;
          #pragma unroll
          for(int fi=0;fi<6;fi++){ const int gt=fi>>1, tt=fi&1;
            giA[fi]=*(const uint2*)&gpp[gt*128+32*w+16*tt+4*q]; }
        }
        int ii=t+2; ii=(ii>LA-1)?(LA-1):ii; ii=(ii<0)?0:ii;
        const int sA2=(LA>0)?eA[ii]:0;
        const bool act=(t<LA);
        #pragma unroll
        for(int tt=0;tt<2;tt++)
          #pragma unroll
          for(int r=0;r<4;r++){
            float rr=sigmf(gv[tt][r]+acc[tt][r]);
            float zz=sigmf(gv[2+tt][r]+acc[2+tt][r]);
            float nn=tanh_fast(gv[4+tt][r]+rr*(acc[4+tt][r]+bhn[tt][r]));
            float hn=nn+zz*(hA[tt][r]-nn);
            hA[tt][r]=act?hn:hA[tt][r];
          }
        {
          unsigned short a0=f2h(hA[0][0]),a1=f2h(hA[0][1]),a2=f2h(hA[0][2]),a3=f2h(hA[0][3]);
          unsigned short b0=f2h(hA[0][0]-h2f(a0)),b1=f2h(hA[0][1]-h2f(a1));
          unsigned short b2=f2h(hA[0][2]-h2f(a2)),b3=f2h(hA[0][3]-h2f(a3));
          *(uint2*)(wA0)      =make_uint2((unsigned)a0|((unsigned)a1<<16),(unsigned)a2|((unsigned)a3<<16));
          *(uint2*)(wA0+4096) =make_uint2((unsigned)b0|((unsigned)b1<<16),(unsigned)b2|((unsigned)b3<<16));
          unsigned short c0=f2h(hA[1][0]),c1=f2h(hA[1][1]),c2=f2h(hA[1][2]),c3=f2h(hA[1][3]);
          unsigned short d0=f2h(hA[1][0]-h2f(c0)),d1=f2h(hA[1][1]-h2f(c1));
          unsigned short d2=f2h(hA[1][2]-h2f(c2)),d3=f2h(hA[1][3]-h2f(c3));
          *(uint2*)(wA1)      =make_uint2((unsigned)c0|((unsigned)c1<<16),(unsigned)c2|((unsigned)c3<<16));
          *(uint2*)(wA1+4096) =make_uint2((unsigned)d0|((unsigned)d1<<16),(unsigned)d2|((unsigned)d3<<16));
        }
        sNA=sA2;
      }
      // ================= group B =================  (grp base +16384)
      {
        f16x8 Bf[4][2];
        #pragma unroll
        for(int p=0;p<2;p++){
          Bf[0][p]=*(const f16x8*)(rA0 + 16384 + p*4096);
          Bf[1][p]=*(const f16x8*)(rA1 + 16384 + p*4096);
          Bf[2][p]=*(const f16x8*)(rA2 + 16384 + p*4096);
          Bf[3][p]=*(const f16x8*)(rA3 + 16384 + p*4096);
        }
        f32x4 acc[6];
        #pragma unroll
        for(int fi=0;fi<6;fi++){
          f32x4 a={0.f,0.f,0.f,0.f};
          #pragma unroll
          for(int ks=0;ks<4;ks++) a=__builtin_amdgcn_mfma_f32_16x16x32_f16(Wf[fi][ks],Bf[ks][1],a,0,0,0);
          #pragma unroll
          for(int ks=0;ks<4;ks++) a=__builtin_amdgcn_mfma_f32_16x16x32_f16(Wf[fi][ks],Bf[ks][0],a,0,0,0);
          acc[fi]=a;
        }
        float gv[6][4];
        #pragma unroll
        for(int fi=0;fi<6;fi++){
          gv[fi][0]=h2f((unsigned short)(giB[fi].x&0xffffu));
          gv[fi][1]=h2f((unsigned short)(giB[fi].x>>16));
          gv[fi][2]=h2f((unsigned short)(giB[fi].y&0xffffu));
          gv[fi][3]=h2f((unsigned short)(giB[fi].y>>16));
        }
        if(t+1<T){
          const unsigned short* gpp=GIh+(size_t)sNB*384;
          #pragma unroll
          for(int fi=0;fi<6;fi++){ const int gt=fi>>1, tt=fi&1;
            giB[fi]=*(const uint2*)&gpp[gt*128+32*w+16*tt+4*q]; }
        }
        int ii=t+2; ii=(ii>LB-1)?(LB-1):ii; ii=(ii<0)?0:ii;
        const int sB2=(LB>0)?eB[ii]:0;
        const bool act=(t<LB);
        #pragma unroll
        for(int tt=0;tt<2;tt++)
          #pragma unroll
          for(int r=0;r<4;r++){
            float rr=sigmf(gv[tt][r]+acc[tt][r]);
            float zz=sigmf(gv[2+tt][r]+acc[2+tt][r]);
            float nn=tanh_fast(gv[4+tt][r]+rr*(acc[4+tt][r]+bhn[tt][r]));
            float hn=nn+zz*(hB[tt][r]-nn);
            hB[tt][r]=act?hn:hB[tt][r];
          }
        {
          unsigned short a0=f2h(hB[0][0]),a1=f2h(hB[0][1]),a2=f2h(hB[0][2]),a3=f2h(hB[0][3]);
          unsigned short b0=f2h(hB[0][0]-h2f(a0)),b1=f2h(hB[0][1]-h2f(a1));
          unsigned short b2=f2h(hB[0][2]-h2f(a2)),b3=f2h(hB[0][3]-h2f(a3));
          *(uint2*)(wA0+16384)      =make_uint2((unsigned)a0|((unsigned)a1<<16),(unsigned)a2|((unsigned)a3<<16));
          *(uint2*)(wA0+16384+4096) =make_uint2((unsigned)b0|((unsigned)b1<<16),(unsigned)b2|((unsigned)b3<<16));
          unsigned short c0=f2h(hB[1][0]),c1=f2h(hB[1][1]),c2=f2h(hB[1][2]),c3=f2h(hB[1][3]);
          unsigned short d0=f2h(hB[1][0]-h2f(c0)),d1=f2h(hB[1][1]-h2f(c1));
          unsigned short d2=f2h(hB[1][2]-h2f(c2)),d3=f2h(hB[1][3]-h2f(c3));
          *(uint2*)(wA1+16384)      =make_uint2((unsigned)c0|((unsigned)c1<<16),(unsigned)c2|((unsigned)c3<<16));
          *(uint2*)(wA1+16384+4096) =make_uint2((unsigned)d0|((unsigned)d1<<16),(unsigned)d2|((unsigned)d3<<16));
        }
        sNB=sB2;
      }
      __syncthreads();
    }
    const int fb=T&1;
    // epilogue: out += W_neigh · h_final (hi+lo planes) from LDS WnL
    #pragma unroll
    for(int tt=0;tt<2;tt++){
      f32x4 a={0.f,0.f,0.f,0.f};
      #pragma unroll
      for(int ks=0;ks<4;ks++){
        const char* ap=(const char*)WnL + (32*w+16*tt+g)*256 + (((4*ks+q)^(g&7))<<4);
        const f16x8 Af=*(const f16x8*)ap;
        const char* bl=(const char*)hbuf + ((fb*2+1)*16+g)*256 + (((4*ks+q)^(g&7))<<4);
        const char* bhp=(const char*)hbuf + ((fb*2+0)*16+g)*256 + (((4*ks+q)^(g&7))<<4);
        a=__builtin_amdgcn_mfma_f32_16x16x32_f16(Af,*(const f16x8*)bl,a,0,0,0);
        a=__builtin_amdgcn_mfma_f32_16x16x32_f16(Af,*(const f16x8*)bhp,a,0,0,0);
      }
      float* po=&out[(size_t)nA*DIM + 32*w+16*tt+4*q];
      float4 cur=*(float4*)po;
      cur.x+=a[0]; cur.y+=a[1]; cur.z+=a[2]; cur.w+=a[3];
      *(float4*)po=cur;
    }
    if(gvB){
      #pragma unroll
      for(int tt=0;tt<2;tt++){
        f32x4 a={0.f,0.f,0.f,0.f};
        #pragma unroll
        for(int ks=0;ks<4;ks++){
          const char* ap=(const char*)WnL + (32*w+16*tt+g)*256 + (((4*ks+q)^(g&7))<<4);
          const f16x8 Af=*(const f16x8*)ap;
          const char* bl=(const char*)hbuf + (((2+fb)*2+1)*16+g)*256 + (((4*ks+q)^(g&7))<<4);
          const char* bhp=(const char*)hbuf + (((2+fb)*2+0)*16+g)*256 + (((4*ks+q)^(g&7))<<4);
          a=__builtin_amdgcn_mfma_f32_16x16x32_f16(Af,*(const f16x8*)bl,a,0,0,0);
          a=__builtin_amdgcn_mfma_f32_16x16x32_f16(Af,*(const f16x8*)bhp,a,0,0,0);
        }
        float* po=&out[(size_t)nB*DIM + 32*w+16*tt+4*q];
        float4 cur=*(float4*)po;
        cur.x+=a[0]; cur.y+=a[1]; cur.z+=a[2]; cur.w+=a[3];
        *(float4*)po=cur;
      }
    }
  }
}

extern "C" void kernel_launch(void* const* d_in, const int* in_sizes, int n_in,
                              void* d_out, int out_size, void* d_ws, size_t ws_size,
                              hipStream_t stream){
  const float* feat  = (const float*)d_in[0];
  const int*   src   = (const int*)d_in[1];
  const int*   dst   = (const int*)d_in[2];
  const float* gamma = (const float*)d_in[3];
  const float* beta  = (const float*)d_in[4];
  const float* Wih   = (const float*)d_in[5];
  const float* Whh   = (const float*)d_in[6];
  const float* bih   = (const float*)d_in[7];
  const float* bhh   = (const float*)d_in[8];
  const float* Wself = (const float*)d_in[9];
  const float* Wneigh= (const float*)d_in[10];
  float* out = (float*)d_out;

  char* ws = (char*)d_ws;
  size_t off = 0;
  auto alloc = [&](size_t bytes)->void*{ void* p = ws+off; off += (bytes+511)&~(size_t)511; return p; };
  float* P     = (float*)alloc(256*128*4);
  float* P2    = (float*)alloc(256*128*4);
  float* scale = (float*)alloc(512);
  float* shift = (float*)alloc(512);
  int*   cnt   = (int*)alloc((size_t)N_NODES*4);
  int*   lenp  = (int*)alloc((size_t)N_NODES*4);
  int*   blockHist = (int*)alloc((size_t)(MAXD+1)*NBLK*4);
  int*   blockBase = (int*)alloc((size_t)(MAXD+1)*NBLK*4);
  int*   perm  = (int*)alloc((size_t)N_NODES*4);
  int*   elist = (int*)alloc((size_t)N_NODES*CAP*4);
  unsigned short* GIh = (unsigned short*)alloc((size_t)N_NODES*384*2);

  kZero<<<(N_NODES+255)/256, 256, 0, stream>>>(cnt, N_NODES);
  kColStats<<<256,128,0,stream>>>(feat, P, P2);
  kFinStats<<<1,128,0,stream>>>(P,P2,gamma,beta,scale,shift);
  kEdges<<<1024,256,0,stream>>>(dst, cnt, elist);
  kSortW<<<(N_NODES+3)/4,256,0,stream>>>(src, cnt, elist, lenp);
  kHistB<<<NBLK,256,0,stream>>>(lenp, blockHist);
  kScanB<<<1,64,0,stream>>>(blockHist, blockBase);
  kScatterB<<<NBLK,256,0,stream>>>(lenp, blockBase, perm);
  kXG2<<<256,256,0,stream>>>(feat, scale, shift, Wih, bih, bhh, Wself, GIh, out);
  kGruM<<<512,256,0,stream>>>(GIh, elist, lenp, perm, Whh, bhh, Wneigh, out);
}